// Round 2
// baseline (6861.893 us; speedup 1.0000x reference)
//
#include <hip/hip_runtime.h>

typedef unsigned short u16;
typedef __attribute__((ext_vector_type(8))) short short8;
typedef __attribute__((ext_vector_type(4))) float f32x4;

#define T_ 70
#define B_ 80
#define V_ 33278
#define E_ 400
#define H_ 1150
#define EP 416      // 400 padded to K-mult of 32
#define HP 1152     // 1150 padded
#define G1 4600     // 4*H
#define G1P 4608
#define G3 1600     // 4*E
#define VP 33280    // 260*128
#define M_ 5600     // T*B
#define MP 5632     // 44*128

__device__ __forceinline__ u16 f2bf(float f) {
  unsigned u = __builtin_bit_cast(unsigned, f);
  u = (u + 0x7fffu + ((u >> 16) & 1u)) >> 16;   // round-to-nearest-even
  return (u16)u;
}

__device__ __forceinline__ void gload16(const void* g, void* l) {
  __builtin_amdgcn_global_load_lds((const __attribute__((address_space(1))) void*)g,
                                   (__attribute__((address_space(3))) void*)l, 16, 0, 0);
}

// ---------------- prep kernels ----------------

__global__ void zero_k(float4* p, long n4) {
  long i = (long)blockIdx.x * blockDim.x + threadIdx.x;
  long stride = (long)gridDim.x * blockDim.x;
  float4 z = {0.f, 0.f, 0.f, 0.f};
  for (; i < n4; i += stride) p[i] = z;
}

__global__ void convert_pad(const float* __restrict__ src, u16* __restrict__ dst,
                            int R, int C, int Cp) {
  int c = blockIdx.x * 256 + threadIdx.x;
  int r = blockIdx.y;
  if (c < Cp) {
    float v = (r < R && c < C) ? src[(size_t)r * C + c] : 0.f;
    dst[(size_t)r * Cp + c] = f2bf(v);
  }
}

__global__ void embed_k(const int* __restrict__ ids, const float* __restrict__ We,
                        u16* __restrict__ x) {
  int r = blockIdx.x;                 // 0..5599
  int tok = ids[r];
  const float* s = We + (size_t)tok * E_;
  u16* d = x + (size_t)r * EP;
  for (int j = threadIdx.x; j < E_; j += 256) d[j] = f2bf(s[j]);
}

__global__ void stinit_k(const float* __restrict__ s, u16* __restrict__ dst, int H, int Kp) {
  int i = blockIdx.x * 256 + threadIdx.x;
  if (i < B_ * Kp) {
    int r = i / Kp, j = i - r * Kp;
    dst[i] = f2bf(j < H ? s[r * H + j] : 0.f);
  }
}

__global__ void cpy_k(float* __restrict__ d, const float* __restrict__ s, int n) {
  int i = blockIdx.x * 256 + threadIdx.x;
  if (i < n) d[i] = s[i];
}

__global__ void badd_k(float* __restrict__ d, const float* __restrict__ a,
                       const float* __restrict__ b, int n) {
  int i = blockIdx.x * 256 + threadIdx.x;
  if (i < n) d[i] = a[i] + b[i];
}

// ---------------- big GEMM: C[M][ldc] = A[Mp][Kp] * B[Np][Kp]^T (+bias) ----------------
__global__ __launch_bounds__(256) void gemm_bt(
    const u16* __restrict__ A, const u16* __restrict__ B,
    float* __restrict__ C, const float* __restrict__ bias,
    int M, int Nstore, int Kp, long ldc)
{
  __shared__ u16 lA[128 * 32];
  __shared__ u16 lB[128 * 32];
  const int tid = threadIdx.x;
  const int bm = blockIdx.y, bn = blockIdx.x;
  const int KS = Kp >> 5;
  const int wid = tid >> 6, lane = tid & 63;
  const int wm = (wid >> 1) << 6, wn = (wid & 1) << 6;
  const int lr = lane & 15, lk = lane >> 4;
  f32x4 acc[4][4] = {};
  const u16* Ab = A + (size_t)bm * 128 * Kp;
  const u16* Bb = B + (size_t)bn * 128 * Kp;
  const int sr = tid >> 2;
  const int sc = (tid & 3) << 3;
  for (int ks = 0; ks < KS; ++ks) {
    const int k0 = ks << 5;
    gload16(Ab + (size_t)sr * Kp + k0 + sc, &lA[tid * 8]);
    gload16(Ab + (size_t)(sr + 64) * Kp + k0 + sc, &lA[2048 + tid * 8]);
    gload16(Bb + (size_t)sr * Kp + k0 + sc, &lB[tid * 8]);
    gload16(Bb + (size_t)(sr + 64) * Kp + k0 + sc, &lB[2048 + tid * 8]);
    __syncthreads();
    short8 av[4], bv[4];
#pragma unroll
    for (int mi = 0; mi < 4; ++mi)
      av[mi] = *(const short8*)&lA[(wm + mi * 16 + lr) * 32 + lk * 8];
#pragma unroll
    for (int ni = 0; ni < 4; ++ni)
      bv[ni] = *(const short8*)&lB[(wn + ni * 16 + lr) * 32 + lk * 8];
#pragma unroll
    for (int mi = 0; mi < 4; ++mi)
#pragma unroll
      for (int ni = 0; ni < 4; ++ni)
        acc[mi][ni] = __builtin_amdgcn_mfma_f32_16x16x32_bf16(av[mi], bv[ni], acc[mi][ni], 0, 0, 0);
    __syncthreads();
  }
  const int rb = bm * 128 + wm, cb = bn * 128 + wn;
#pragma unroll
  for (int ni = 0; ni < 4; ++ni) {
    const int cn = cb + ni * 16 + lr;
    if (cn >= Nstore) continue;
    const float badd = bias ? bias[cn] : 0.f;
#pragma unroll
    for (int mi = 0; mi < 4; ++mi) {
      const int r0 = rb + mi * 16 + lk * 4;
#pragma unroll
      for (int r = 0; r < 4; ++r) {
        const int rr = r0 + r;
        if (rr < M) C[(size_t)rr * ldc + cn] = acc[mi][ni][r] + badd;
      }
    }
  }
}

// ---------------- pipelined LSTM step: 3 layers in one launch ----------------
// blocks [0,72): layer1 t=s      (xg precomputed, 1 matmul pair)
// blocks [72,144): layer2 t=s-1  (2 pairs: Whh2@h2prev + Wih2@h1[t])
// blocks [144,169): layer3 t=s-2 (2 pairs: Whh3@h3prev + Wih3@h2[t])
struct LayerArgs {
  const float* xg;           // fp32 precomputed input gates, or null
  const u16* Wa; const u16* Xa;   // pair A: W [4H][Kpa] bf16, X [80][Kpa] bf16
  const u16* Wb; const u16* Xb;   // pair B (optional)
  const float* b;            // bih+bhh [4H]
  float* cbuf; float* hstate; u16* hout;
  int ldxg, Kpa, KSa, Kpb, KSb, H, Kp_out, active;
};

__global__ __launch_bounds__(512) void lstm_step3(LayerArgs L0, LayerArgs L1, LayerArgs L2) {
  __shared__ float gl[B_ * 64];
  const int blk = blockIdx.x;
  LayerArgs L; int jblk;
  if (blk < 72)       { L = L0; jblk = blk; }
  else if (blk < 144) { L = L1; jblk = blk - 72; }
  else                { L = L2; jblk = blk - 144; }
  if (!L.active) return;
  const int tid = threadIdx.x;
  const int wid = tid >> 6, lane = tid & 63;
  const int lr = lane & 15, lk = lane >> 4;
  const int j0 = jblk << 4;
  for (int i = tid; i < B_ * 64; i += 512) gl[i] = 0.f;
  __syncthreads();
  const int KSt = L.KSa + L.KSb;
  const int gs0 = (wid * KSt) >> 3, gs1 = ((wid + 1) * KSt) >> 3;
  f32x4 acc[5][4] = {};
  for (int gs = gs0; gs < gs1; ++gs) {
    const u16* Wp; const u16* Xp; int Kp, k0;
    if (gs < L.KSa) { Wp = L.Wa; Xp = L.Xa; Kp = L.Kpa; k0 = gs << 5; }
    else            { Wp = L.Wb; Xp = L.Xb; Kp = L.Kpb; k0 = (gs - L.KSa) << 5; }
    const int kk = k0 + (lk << 3);
    short8 av[5], bv[4];
#pragma unroll
    for (int mf = 0; mf < 5; ++mf)
      av[mf] = *(const short8*)&Xp[(size_t)(mf * 16 + lr) * Kp + kk];
#pragma unroll
    for (int g = 0; g < 4; ++g)
      bv[g] = *(const short8*)&Wp[(size_t)(g * L.H + j0 + lr) * Kp + kk];
#pragma unroll
    for (int mf = 0; mf < 5; ++mf)
#pragma unroll
      for (int g = 0; g < 4; ++g)
        acc[mf][g] = __builtin_amdgcn_mfma_f32_16x16x32_bf16(av[mf], bv[g], acc[mf][g], 0, 0, 0);
  }
#pragma unroll
  for (int mf = 0; mf < 5; ++mf)
#pragma unroll
    for (int g = 0; g < 4; ++g)
#pragma unroll
      for (int r = 0; r < 4; ++r)
        atomicAdd(&gl[(mf * 16 + lk * 4 + r) * 64 + g * 16 + lr], acc[mf][g][r]);
  __syncthreads();
  const int H = L.H;
  for (int i = tid; i < B_ * 16; i += 512) {
    const int row = i >> 4, jj = i & 15, j = j0 + jj;
    if (j < H) {
      const float* xr = L.xg ? L.xg + (size_t)row * L.ldxg : nullptr;
      float vi = gl[row * 64 + jj]      + (xr ? xr[j]         : 0.f) + L.b[j];
      float vf = gl[row * 64 + 16 + jj] + (xr ? xr[H + j]     : 0.f) + L.b[H + j];
      float vg = gl[row * 64 + 32 + jj] + (xr ? xr[2 * H + j] : 0.f) + L.b[2 * H + j];
      float vo = gl[row * 64 + 48 + jj] + (xr ? xr[3 * H + j] : 0.f) + L.b[3 * H + j];
      float si = 1.f / (1.f + __expf(-vi));
      float sf = 1.f / (1.f + __expf(-vf));
      float tg = tanhf(vg);
      float so = 1.f / (1.f + __expf(-vo));
      float c = sf * L.cbuf[row * H + j] + si * tg;
      L.cbuf[row * H + j] = c;
      float h = so * tanhf(c);
      L.hstate[row * H + j] = h;
      L.hout[(size_t)row * L.Kp_out + j] = f2bf(h);
    }
  }
}

// ---------------- final-state copy into d_out tail ----------------
__global__ void tail_k(const float* __restrict__ h1, const float* __restrict__ c1,
                       const float* __restrict__ h2, const float* __restrict__ c2,
                       const float* __restrict__ h3, const float* __restrict__ c3,
                       float* __restrict__ out) {
  int i = blockIdx.x * 256 + threadIdx.x;
  const long base = (long)M_ * V_;
  if (i < 92000)       out[base + i] = h1[i];
  else if (i < 184000) out[base + i] = c1[i - 92000];
  else if (i < 276000) out[base + i] = h2[i - 184000];
  else if (i < 368000) out[base + i] = c2[i - 276000];
  else if (i < 400000) out[base + i] = h3[i - 368000];
  else if (i < 432000) out[base + i] = c3[i - 400000];
}

// ---------------- host ----------------

extern "C" void kernel_launch(void* const* d_in, const int* in_sizes, int n_in,
                              void* d_out, int out_size, void* d_ws, size_t ws_size,
                              hipStream_t stream)
{
  const int*   ids  = (const int*)d_in[0];
  const float* s1h  = (const float*)d_in[1];
  const float* s1c  = (const float*)d_in[2];
  const float* s2h  = (const float*)d_in[3];
  const float* s2c  = (const float*)d_in[4];
  const float* s3h  = (const float*)d_in[5];
  const float* s3c  = (const float*)d_in[6];
  const float* Wemb = (const float*)d_in[7];
  const float* fcb  = (const float*)d_in[8];
  const float* Wih1 = (const float*)d_in[9];
  const float* Whh1 = (const float*)d_in[10];
  const float* bih1 = (const float*)d_in[11];
  const float* bhh1 = (const float*)d_in[12];
  const float* Wih2 = (const float*)d_in[13];
  const float* Whh2 = (const float*)d_in[14];
  const float* bih2 = (const float*)d_in[15];
  const float* bhh2 = (const float*)d_in[16];
  const float* Wih3 = (const float*)d_in[17];
  const float* Whh3 = (const float*)d_in[18];
  const float* bih3 = (const float*)d_in[19];
  const float* bhh3 = (const float*)d_in[20];
  float* out = (float*)d_out;

  char* p = (char*)d_ws;
  auto alloc = [&](size_t bytes) -> char* {
    char* r = p; p += (bytes + 255) & ~(size_t)255; return r;
  };
  u16* WembP = (u16*)alloc((size_t)VP * EP * 2);
  u16* Wih1P = (u16*)alloc((size_t)G1P * EP * 2);
  u16* Whh1P = (u16*)alloc((size_t)G1P * HP * 2);
  u16* Wih2P = (u16*)alloc((size_t)G1P * HP * 2);
  u16* Whh2P = (u16*)alloc((size_t)G1P * HP * 2);
  u16* Wih3P = (u16*)alloc((size_t)G3 * HP * 2);
  u16* Whh3P = (u16*)alloc((size_t)G3 * EP * 2);
  char* zs = p;  // ---- start of zero-initialized region ----
  u16* xb  = (u16*)alloc((size_t)MP * EP * 2);
  u16* h1a = (u16*)alloc((size_t)MP * HP * 2);
  u16* h2a = (u16*)alloc((size_t)MP * HP * 2);
  u16* h3a = (u16*)alloc((size_t)MP * EP * 2);
  u16* h1i = (u16*)alloc((size_t)B_ * HP * 2);
  u16* h2i = (u16*)alloc((size_t)B_ * HP * 2);
  u16* h3i = (u16*)alloc((size_t)B_ * EP * 2);
  char* ze = p;  // ---- end of zero region ----
  float* xg1 = (float*)alloc((size_t)M_ * G1P * 4);
  float* c1  = (float*)alloc((size_t)B_ * H_ * 4);
  float* c2  = (float*)alloc((size_t)B_ * H_ * 4);
  float* c3  = (float*)alloc((size_t)B_ * E_ * 4);
  float* h1s = (float*)alloc((size_t)B_ * H_ * 4);
  float* h2s = (float*)alloc((size_t)B_ * H_ * 4);
  float* h3s = (float*)alloc((size_t)B_ * E_ * 4);
  float* b1  = (float*)alloc((size_t)G1 * 4);
  float* b2  = (float*)alloc((size_t)G1 * 4);
  float* b3  = (float*)alloc((size_t)G3 * 4);
  (void)ws_size; (void)in_sizes; (void)n_in; (void)out_size;

  long zn4 = (long)((ze - zs) >> 4);
  zero_k<<<dim3(2048), dim3(256), 0, stream>>>((float4*)zs, zn4);

  convert_pad<<<dim3(2, VP), dim3(256), 0, stream>>>(Wemb, WembP, V_, E_, EP);
  convert_pad<<<dim3(2, G1P), dim3(256), 0, stream>>>(Wih1, Wih1P, G1, E_, EP);
  convert_pad<<<dim3(5, G1P), dim3(256), 0, stream>>>(Whh1, Whh1P, G1, H_, HP);
  convert_pad<<<dim3(5, G1P), dim3(256), 0, stream>>>(Wih2, Wih2P, G1, H_, HP);
  convert_pad<<<dim3(5, G1P), dim3(256), 0, stream>>>(Whh2, Whh2P, G1, H_, HP);
  convert_pad<<<dim3(5, G3), dim3(256), 0, stream>>>(Wih3, Wih3P, G3, H_, HP);
  convert_pad<<<dim3(2, G3), dim3(256), 0, stream>>>(Whh3, Whh3P, G3, E_, EP);

  embed_k<<<dim3(M_), dim3(256), 0, stream>>>(ids, Wemb, xb);
  stinit_k<<<dim3(360), dim3(256), 0, stream>>>(s1h, h1i, H_, HP);
  stinit_k<<<dim3(360), dim3(256), 0, stream>>>(s2h, h2i, H_, HP);
  stinit_k<<<dim3(130), dim3(256), 0, stream>>>(s3h, h3i, E_, EP);
  cpy_k<<<dim3(360), dim3(256), 0, stream>>>(c1, s1c, B_ * H_);
  cpy_k<<<dim3(360), dim3(256), 0, stream>>>(c2, s2c, B_ * H_);
  cpy_k<<<dim3(125), dim3(256), 0, stream>>>(c3, s3c, B_ * E_);
  badd_k<<<dim3(18), dim3(256), 0, stream>>>(b1, bih1, bhh1, G1);
  badd_k<<<dim3(18), dim3(256), 0, stream>>>(b2, bih2, bhh2, G1);
  badd_k<<<dim3(7), dim3(256), 0, stream>>>(b3, bih3, bhh3, G3);

  // xg1 = x @ Wih1^T  (only layer 1's input projection is precomputable)
  gemm_bt<<<dim3(G1P / 128, MP / 128), dim3(256), 0, stream>>>(
      xb, Wih1P, xg1, nullptr, M_, G1P, EP, G1P);

  // pipelined recurrence: 72 launches, 169 WGs each
  for (int s = 0; s < 72; ++s) {
    LayerArgs L0 = {}, L1 = {}, L2 = {};
    if (s < 70) {                      // layer1, t=s
      int t = s;
      L0.active = 1; L0.xg = xg1 + (size_t)t * B_ * G1P; L0.ldxg = G1P;
      L0.Wa = Whh1P; L0.Xa = t ? h1a + (size_t)(t - 1) * B_ * HP : h1i;
      L0.Kpa = HP; L0.KSa = HP / 32; L0.KSb = 0;
      L0.b = b1; L0.cbuf = c1; L0.hstate = h1s;
      L0.hout = h1a + (size_t)t * B_ * HP; L0.H = H_; L0.Kp_out = HP;
    }
    if (s >= 1 && s <= 70) {           // layer2, t=s-1
      int t = s - 1;
      L1.active = 1; L1.xg = nullptr;
      L1.Wa = Whh2P; L1.Xa = t ? h2a + (size_t)(t - 1) * B_ * HP : h2i;
      L1.Kpa = HP; L1.KSa = HP / 32;
      L1.Wb = Wih2P; L1.Xb = h1a + (size_t)t * B_ * HP;
      L1.Kpb = HP; L1.KSb = HP / 32;
      L1.b = b2; L1.cbuf = c2; L1.hstate = h2s;
      L1.hout = h2a + (size_t)t * B_ * HP; L1.H = H_; L1.Kp_out = HP;
    }
    if (s >= 2) {                      // layer3, t=s-2
      int t = s - 2;
      L2.active = 1; L2.xg = nullptr;
      L2.Wa = Whh3P; L2.Xa = t ? h3a + (size_t)(t - 1) * B_ * EP : h3i;
      L2.Kpa = EP; L2.KSa = EP / 32;
      L2.Wb = Wih3P; L2.Xb = h2a + (size_t)t * B_ * HP;
      L2.Kpb = HP; L2.KSb = HP / 32;
      L2.b = b3; L2.cbuf = c3; L2.hstate = h3s;
      L2.hout = h3a + (size_t)t * B_ * EP; L2.H = E_; L2.Kp_out = EP;
    }
    lstm_step3<<<dim3(169), dim3(512), 0, stream>>>(L0, L1, L2);
  }

  // scores = h3_all @ W_emb^T + fc_b  -> d_out
  gemm_bt<<<dim3(VP / 128, MP / 128), dim3(256), 0, stream>>>(
      h3a, WembP, out, fcb, M_, V_, EP, (long)V_);
  tail_k<<<dim3(1688), dim3(256), 0, stream>>>(h1s, c1, h2s, c2, h3s, c3, out);
}